// Round 2
// baseline (19.033 us; speedup 1.0000x reference)
//
#include <hip/hip_runtime.h>

// IntrinsicLoss: out[b] = ||A_b w_b||^2, A_b built from X[b,0:6].
// Memory-bound. v2: LDS-staged loads so every global_load_dwordx4 is
// unit-stride across lanes (v1 had 48B/32B lane strides -> 3x cache-line
// lookups per instruction). Each block: 512 rows, 3+2 coalesced float4
// loads/thread -> LDS (20KB, 8 blocks/CU), barrier, compute 2 rows/thread.

__device__ __forceinline__ float row_loss(float x0, float x1, float x2,
                                          float x3, float x4, float x5,
                                          float w0, float w1, float w2, float w3) {
    // row0 = [x0*x2 + x1*x3, x0 + x2, x1 + x3, 1]
    // row1 = [x0*x4 + x1*x5, x0 + x4, x1 + x5, 1]
    // row2 = [x2*x4 + x3*x5, x2 + x4, x3 + x5, 1]
    float r0 = fmaf(fmaf(x0, x2, x1 * x3), w0,
               fmaf(x0 + x2, w1, fmaf(x1 + x3, w2, w3)));
    float r1 = fmaf(fmaf(x0, x4, x1 * x5), w0,
               fmaf(x0 + x4, w1, fmaf(x1 + x5, w2, w3)));
    float r2 = fmaf(fmaf(x2, x4, x3 * x5), w0,
               fmaf(x2 + x4, w1, fmaf(x3 + x5, w2, w3)));
    return fmaf(r0, r0, fmaf(r1, r1, r2 * r2));
}

__global__ __launch_bounds__(256) void IntrinsicLoss_kernel(
    const float4* __restrict__ X4,   // X as float4[]; 768 per full block
    const float4* __restrict__ W4,   // W as float4[]; 512 per full block
    float2* __restrict__ out2,       // out as float2[]; 256 per full block
    int npairs, int odd, int fullBlocks,
    const float* __restrict__ Xs,    // scalar views for the tail
    const float* __restrict__ Ws,
    float* __restrict__ outs)
{
    __shared__ float4 sx[768];   // 512 rows * 6 floats
    __shared__ float4 sw[512];   // 512 rows * 4 floats
    const int t = threadIdx.x;
    const int b = blockIdx.x;

    if (b < fullBlocks) {
        const float4* xg = X4 + (size_t)b * 768;
        const float4* wg = W4 + (size_t)b * 512;
        // unit-stride coalesced staging
        sx[t]       = xg[t];
        sx[t + 256] = xg[t + 256];
        sx[t + 512] = xg[t + 512];
        sw[t]       = wg[t];
        sw[t + 256] = wg[t + 256];
        __syncthreads();

        float4 a  = sx[3 * t + 0];   // xA0 xA1 xA2 xA3
        float4 c1 = sx[3 * t + 1];   // xA4 xA5 xB0 xB1
        float4 c2 = sx[3 * t + 2];   // xB2 xB3 xB4 xB5
        float4 wa = sw[2 * t + 0];
        float4 wb = sw[2 * t + 1];

        float la = row_loss(a.x, a.y, a.z, a.w, c1.x, c1.y,
                            wa.x, wa.y, wa.z, wa.w);
        float lb = row_loss(c1.z, c1.w, c2.x, c2.y, c2.z, c2.w,
                            wb.x, wb.y, wb.z, wb.w);
        out2[(size_t)b * 256 + t] = make_float2(la, lb);
    } else {
        // tail block: leftover pairs via direct (strided) loads + odd row
        int idx = fullBlocks * 256 + t;      // pair index
        if (idx < npairs) {
            float4 a  = X4[idx * 3 + 0];
            float4 c1 = X4[idx * 3 + 1];
            float4 c2 = X4[idx * 3 + 2];
            float4 wa = W4[idx * 2 + 0];
            float4 wb = W4[idx * 2 + 1];
            float la = row_loss(a.x, a.y, a.z, a.w, c1.x, c1.y,
                                wa.x, wa.y, wa.z, wa.w);
            float lb = row_loss(c1.z, c1.w, c2.x, c2.y, c2.z, c2.w,
                                wb.x, wb.y, wb.z, wb.w);
            out2[idx] = make_float2(la, lb);
        } else if (odd && idx == npairs) {
            int r = 2 * npairs;   // last row
            float l = row_loss(Xs[r * 6 + 0], Xs[r * 6 + 1], Xs[r * 6 + 2],
                               Xs[r * 6 + 3], Xs[r * 6 + 4], Xs[r * 6 + 5],
                               Ws[r * 4 + 0], Ws[r * 4 + 1], Ws[r * 4 + 2],
                               Ws[r * 4 + 3]);
            outs[r] = l;
        }
    }
}

extern "C" void kernel_launch(void* const* d_in, const int* in_sizes, int n_in,
                              void* d_out, int out_size, void* d_ws, size_t ws_size,
                              hipStream_t stream) {
    const float* X = (const float*)d_in[0];   // [B, 6] fp32
    const float* W = (const float*)d_in[1];   // [B, 4] fp32
    float* out = (float*)d_out;               // [B] fp32

    int B = in_sizes[0] / 6;
    int npairs = B / 2;
    int odd = B & 1;
    int fullBlocks = npairs / 256;
    int tailThreads = (npairs - fullBlocks * 256) + odd;
    int grid = fullBlocks + (tailThreads > 0 ? 1 : 0);

    IntrinsicLoss_kernel<<<grid, 256, 0, stream>>>(
        (const float4*)X, (const float4*)W, (float2*)out,
        npairs, odd, fullBlocks, X, W, out);
}